// Round 12
// baseline (49.211 us; speedup 1.0000x reference)
//
#include <hip/hip_runtime.h>
#include <hip/hip_fp16.h>

// Problem constants (match reference)
constexpr int B = 32, S = 4096, D = 64;
constexpr float EPS_DIV = 1e-8f;
constexpr float EPS_LN  = 1e-5f;

// Group-parallel decomposition: 16-lane groups, float4 channels (R8/R10 geometry)
constexpr int NCG = 512;         // sub-chunks per sequence
constexpr int LG  = S / NCG;     // 8 steps per sub-chunk
constexpr int CPL = NCG / 64;    // chunks per lane in phase-2 scans = 8
constexpr int BPB = NCG / 16;    // blocks per batch = 32

struct alignas(16) H2x4 { __half2 a, b, c, d; };   // 4x {hi,lo} half2

typedef float        f4v __attribute__((ext_vector_type(4)));
typedef unsigned int u2v __attribute__((ext_vector_type(2)));

__device__ __forceinline__ void nt_store_f4(float4 v, float4* p) {
    f4v t = {v.x, v.y, v.z, v.w};
    __builtin_nontemporal_store(t, (f4v*)p);
}

__device__ __forceinline__ float sigmoid_f(float x) {
    return __builtin_amdgcn_rcpf(1.f + __expf(-x));
}

// ---------------- Phase 1: per-chunk summaries (fp32 path, no side-store) ----------------
// Cross-lane reductions deferred out of the carried loop (R10 structure).
// P/O computed in fp32 in EXACTLY the op order k3r uses for its replay.
__global__ __launch_bounds__(256, 4) void k1h(
    const float4* __restrict__ C4, const float4* __restrict__ V4,
    const float4* __restrict__ W4, const float* __restrict__ TM,
    float2* __restrict__ MQstep,                        // [B*S]
    float*  __restrict__ Mc, float* __restrict__ Qc,    // [B*NCG]
    H2x4*   __restrict__ POt)                           // [B][D][NCG/4] fp16 {P,O}x4
{
    __shared__ float sp[64][17];
    __shared__ float so[64][17];

    const int t = threadIdx.x;
    const int g = t >> 4;                  // group in block (= local c)
    const int r = t & 15;
    const int G = blockIdx.x * 16 + g;
    const int b = G >> 9;                  // / NCG
    const int c = G & (NCG - 1);
    const int c0 = (blockIdx.x & (BPB - 1)) * 16;
    const int s0 = c * LG;
    const size_t base = (size_t)(b * S + s0) * 16 + r;  // float4-quad index
    const float4 tm = reinterpret_cast<const float4*>(TM)[r];

    float psd[LG], pse[LG];                // per-lane partial sums (deferred)
    float4 P = {1.f, 1.f, 1.f, 1.f}, O = {0.f, 0.f, 0.f, 0.f};
#pragma unroll
    for (int i = 0; i < LG; ++i) {
        const size_t idx = base + (size_t)i * 16;
        const float4 w = W4[idx], cc = C4[idx], v = V4[idx];
        float4 dg, ec;
        dg.x = sigmoid_f(w.x * tm.x); dg.y = sigmoid_f(w.y * tm.y);
        dg.z = sigmoid_f(w.z * tm.z); dg.w = sigmoid_f(w.w * tm.w);
        ec.x = __expf(cc.x); ec.y = __expf(cc.y);
        ec.z = __expf(cc.z); ec.w = __expf(cc.w);
        psd[i] = (dg.x + dg.y) + (dg.z + dg.w);
        pse[i] = (ec.x + ec.y) + (ec.z + ec.w);
        P.x *= dg.x; P.y *= dg.y; P.z *= dg.z; P.w *= dg.w;
        O.x = fmaf(dg.x, O.x, ec.x * v.x);
        O.y = fmaf(dg.y, O.y, ec.y * v.y);
        O.z = fmaf(dg.z, O.z, ec.z * v.z);
        O.w = fmaf(dg.w, O.w, ec.w * v.w);
    }

    // batched 16-lane butterflies (pipelined across LG chains)
#pragma unroll
    for (int m = 1; m < 16; m <<= 1) {
#pragma unroll
        for (int i = 0; i < LG; ++i) {
            psd[i] += __shfl_xor(psd[i], m, 64);
            pse[i] += __shfl_xor(pse[i], m, 64);
        }
    }
    float M = 1.f, Q = 0.f;
#pragma unroll
    for (int i = 0; i < LG; ++i) {
        const float mm = psd[i] * (1.f / 64.f);
        M *= mm;
        Q  = fmaf(mm, Q, pse[i]);
    }
    if (r == 0) {
#pragma unroll
        for (int i = 0; i < LG; ++i)
            MQstep[b * S + s0 + i] = make_float2(psd[i] * (1.f / 64.f), pse[i]);
        Mc[G] = M; Qc[G] = Q;
    }

    // transpose [16c x 64d] -> [64d x 16c] through LDS; pack fp16 {P,O}
    sp[4*r+0][g] = P.x; sp[4*r+1][g] = P.y; sp[4*r+2][g] = P.z; sp[4*r+3][g] = P.w;
    so[4*r+0][g] = O.x; so[4*r+1][g] = O.y; so[4*r+2][g] = O.z; so[4*r+3][g] = O.w;
    __syncthreads();
    const int d  = t >> 2;                 // 0..63
    const int cq = t & 3;                  // 0..3 (4 chunks each)
    H2x4 po;
    po.a = __floats2half2_rn(sp[d][cq*4+0], so[d][cq*4+0]);
    po.b = __floats2half2_rn(sp[d][cq*4+1], so[d][cq*4+1]);
    po.c = __floats2half2_rn(sp[d][cq*4+2], so[d][cq*4+2]);
    po.d = __floats2half2_rn(sp[d][cq*4+3], so[d][cq*4+3]);
    POt[(size_t)(b * D + d) * (NCG / 4) + (c0 >> 2) + cq] = po;
}

// ---------------- Phase 2: parallel affine scans (vector + scalar) ----------------
__global__ __launch_bounds__(256) void k2(
    const float*  __restrict__ Mc,  const float*  __restrict__ Qc,
    const H2x4*   __restrict__ POt,
    float4* __restrict__ aIn4,      // [B][NCG] fp32
    H2x4*   __restrict__ bInH)      // [B][D][NCG/8] fp16 carries
{
    const int wq   = threadIdx.x >> 6;
    const int lane = threadIdx.x & 63;

    if (blockIdx.x < 512) {
        const int W = blockIdx.x * 4 + wq;      // 0..2047
        const int b = W >> 6, d = W & 63;
        const size_t row4 = (size_t)(b * D + d) * (NCG / 4);
        const H2x4 A = POt[row4 + lane*2], Bq = POt[row4 + lane*2 + 1];
        float pj[CPL], oj[CPL];
        {
            float2 f;
            f = __half22float2(A.a);  pj[0] = f.x; oj[0] = f.y;
            f = __half22float2(A.b);  pj[1] = f.x; oj[1] = f.y;
            f = __half22float2(A.c);  pj[2] = f.x; oj[2] = f.y;
            f = __half22float2(A.d);  pj[3] = f.x; oj[3] = f.y;
            f = __half22float2(Bq.a); pj[4] = f.x; oj[4] = f.y;
            f = __half22float2(Bq.b); pj[5] = f.x; oj[5] = f.y;
            f = __half22float2(Bq.c); pj[6] = f.x; oj[6] = f.y;
            f = __half22float2(Bq.d); pj[7] = f.x; oj[7] = f.y;
        }
        float p = 1.f, o = 0.f;
#pragma unroll
        for (int j = 0; j < CPL; ++j) { o = fmaf(pj[j], o, oj[j]); p = pj[j] * p; }
#pragma unroll
        for (int s = 1; s < 64; s <<= 1) {
            const float pp = __shfl_up(p, s, 64);
            const float oo = __shfl_up(o, s, 64);
            if (lane >= s) { o = fmaf(p, oo, o); p = p * pp; }
        }
        float oe = __shfl_up(o, 1, 64);
        if (lane == 0) oe = 0.f;
        float bv = oe, ob[CPL];
#pragma unroll
        for (int j = 0; j < CPL; ++j) { ob[j] = bv; bv = fmaf(pj[j], bv, oj[j]); }
        H2x4 w;
        w.a = __floats2half2_rn(ob[0], ob[1]);
        w.b = __floats2half2_rn(ob[2], ob[3]);
        w.c = __floats2half2_rn(ob[4], ob[5]);
        w.d = __floats2half2_rn(ob[6], ob[7]);
        bInH[(size_t)(b * D + d) * (NCG / 8) + lane] = w;
    } else {
        const int v = (blockIdx.x - 512) * 4 + wq;
        if (v >= B) return;
        const float4* Mc4 = reinterpret_cast<const float4*>(Mc) + v * (NCG / 4);
        const float4* Qc4 = reinterpret_cast<const float4*>(Qc) + v * (NCG / 4);
        const float4 mA = Mc4[lane*2], mB = Mc4[lane*2 + 1];
        const float4 qA = Qc4[lane*2], qB = Qc4[lane*2 + 1];
        float mj[CPL] = {mA.x, mA.y, mA.z, mA.w, mB.x, mB.y, mB.z, mB.w};
        float qj[CPL] = {qA.x, qA.y, qA.z, qA.w, qB.x, qB.y, qB.z, qB.w};
        float m = 1.f, q = 0.f;
#pragma unroll
        for (int j = 0; j < CPL; ++j) { q = fmaf(mj[j], q, qj[j]); m = mj[j] * m; }
#pragma unroll
        for (int s = 1; s < 64; s <<= 1) {
            const float mm = __shfl_up(m, s, 64);
            const float qq = __shfl_up(q, s, 64);
            if (lane >= s) { q = fmaf(m, qq, q); m = m * mm; }
        }
        float qe = __shfl_up(q, 1, 64);
        if (lane == 0) qe = 0.f;
        float a = qe, ab[CPL];
#pragma unroll
        for (int j = 0; j < CPL; ++j) { ab[j] = a; a = fmaf(mj[j], a, qj[j]); }
        aIn4[v * (NCG / 4) + lane*2]     = make_float4(ab[0], ab[1], ab[2], ab[3]);
        aIn4[v * (NCG / 4) + lane*2 + 1] = make_float4(ab[4], ab[5], ab[6], ab[7]);
    }
}

// ---------------- Phase 3: recompute replay from inputs + fused LayerNorm ----------------
// Reads C/V/W again (L3-resident: workspace is now tiny, out is nt-stored).
// Identical fp32 op order as k1h -> replay matches chunk summaries exactly.
// Deferred LN reductions (R10 structure).
__global__ __launch_bounds__(256, 4) void k3r(
    const float4* __restrict__ C4, const float4* __restrict__ V4,
    const float4* __restrict__ W4, const float* __restrict__ TM,
    const float* __restrict__ Gam, const float* __restrict__ Bet,
    const float2* __restrict__ MQstep,
    const float* __restrict__ aIn, const __half* __restrict__ bInH,
    float4* __restrict__ out4)
{
    __shared__ float sb[64][17];   // [d][local c] carry tile (+1 pad)

    const int t = threadIdx.x;
    const int b  = blockIdx.x >> 5;            // BPB=32 blocks per batch
    const int c0 = (blockIdx.x & (BPB - 1)) * 16;
    {   // coalesced stage of this block's fp16 carry tile (8B per thread)
        const int d = t >> 2, cq = t & 3;
        const u2v raw = *reinterpret_cast<const u2v*>(
            bInH + (size_t)(b * D + d) * NCG + c0 + cq * 4);
        union { unsigned int u; __half2 h; } c0u, c1u;
        c0u.u = raw.x; c1u.u = raw.y;
        const float2 f0 = __half22float2(c0u.h);
        const float2 f1 = __half22float2(c1u.h);
        sb[d][cq*4+0] = f0.x; sb[d][cq*4+1] = f0.y;
        sb[d][cq*4+2] = f1.x; sb[d][cq*4+3] = f1.y;
    }
    __syncthreads();

    const int g = t >> 4;
    const int r = t & 15;
    const int c = c0 + g;
    const int s0 = c * LG;
    const size_t base = (size_t)(b * S + s0) * 16 + r;
    const float4 tm = reinterpret_cast<const float4*>(TM)[r];
    const float4 g4 = reinterpret_cast<const float4*>(Gam)[r];
    const float4 b4 = reinterpret_cast<const float4*>(Bet)[r];

    float a = aIn[b * NCG + c];                // broadcast within group
    float4 bv = make_float4(sb[4*r+0][g], sb[4*r+1][g],
                            sb[4*r+2][g], sb[4*r+3][g]);

    float4 yv[LG];
    float psy[LG], psq[LG];
#pragma unroll
    for (int i = 0; i < LG; ++i) {
        const size_t idx = base + (size_t)i * 16;
        const float4 w = W4[idx], cc = C4[idx], v = V4[idx];
        float4 dg, ec;
        dg.x = sigmoid_f(w.x * tm.x); dg.y = sigmoid_f(w.y * tm.y);
        dg.z = sigmoid_f(w.z * tm.z); dg.w = sigmoid_f(w.w * tm.w);
        ec.x = __expf(cc.x); ec.y = __expf(cc.y);
        ec.z = __expf(cc.z); ec.w = __expf(cc.w);
        const float2 mq = MQstep[b * S + s0 + i];   // uniform within group
        a = fmaf(mq.x, a, mq.y);
        bv.x = fmaf(dg.x, bv.x, ec.x * v.x);
        bv.y = fmaf(dg.y, bv.y, ec.y * v.y);
        bv.z = fmaf(dg.z, bv.z, ec.z * v.z);
        bv.w = fmaf(dg.w, bv.w, ec.w * v.w);
        const float inva = __builtin_amdgcn_rcpf(a + EPS_DIV);
        float4 y;
        y.x = bv.x * inva; y.y = bv.y * inva;
        y.z = bv.z * inva; y.w = bv.w * inva;
        yv[i] = y;
        psy[i] = (y.x + y.y) + (y.z + y.w);
        psq[i] = fmaf(y.x, y.x, y.y * y.y) + fmaf(y.z, y.z, y.w * y.w);
    }
#pragma unroll
    for (int m = 1; m < 16; m <<= 1) {
#pragma unroll
        for (int i = 0; i < LG; ++i) {
            psy[i] += __shfl_xor(psy[i], m, 64);
            psq[i] += __shfl_xor(psq[i], m, 64);
        }
    }
#pragma unroll
    for (int i = 0; i < LG; ++i) {
        const float4 y = yv[i];
        const float mu  = psy[i] * (1.f / 64.f);
        const float var = fmaf(-mu, mu, psq[i] * (1.f / 64.f));
        const float rs  = __builtin_amdgcn_rsqf(fmaxf(var, 0.f) + EPS_LN);
        float4 o;
        o.x = fmaf((y.x - mu) * rs, g4.x, b4.x);
        o.y = fmaf((y.y - mu) * rs, g4.y, b4.y);
        o.z = fmaf((y.z - mu) * rs, g4.z, b4.z);
        o.w = fmaf((y.w - mu) * rs, g4.w, b4.w);
        nt_store_f4(o, &out4[base + (size_t)i * 16]);
    }
}

// ---------------- Fallback (only if workspace unexpectedly small) ----------------
__global__ __launch_bounds__(64) void k_naive(
    const float* __restrict__ Cp, const float* __restrict__ Vp,
    const float* __restrict__ Wp, const float* __restrict__ TM,
    const float* __restrict__ Gam, const float* __restrict__ Bet,
    float* __restrict__ out)
{
    const int b = blockIdx.x;
    const int lane = threadIdx.x;
    const float tm = TM[lane], g = Gam[lane], bt = Bet[lane];
    float a = 0.f, bv = 0.f;
    for (int s = 0; s < S; ++s) {
        const size_t idx = ((size_t)b * S + s) * D + lane;
        const float wv = Wp[idx], cv = Cp[idx], vv = Vp[idx];
        const float dg = sigmoid_f(wv * tm);
        const float ec = __expf(cv);
        float sd = dg, se = ec;
#pragma unroll
        for (int m = 1; m < 64; m <<= 1) {
            sd += __shfl_xor(sd, m, 64);
            se += __shfl_xor(se, m, 64);
        }
        a  = fmaf(sd * (1.f / 64.f), a, se);
        bv = fmaf(dg, bv, ec * vv);
        const float y = bv * __builtin_amdgcn_rcpf(a + EPS_DIV);
        float sy = y, sq = y * y;
#pragma unroll
        for (int m = 1; m < 64; m <<= 1) {
            sy += __shfl_xor(sy, m, 64);
            sq += __shfl_xor(sq, m, 64);
        }
        const float mu  = sy * (1.f / 64.f);
        const float var = fmaf(-mu, mu, sq * (1.f / 64.f));
        const float rs  = __builtin_amdgcn_rsqf(fmaxf(var, 0.f) + EPS_LN);
        out[idx] = fmaf((y - mu) * rs, g, bt);
    }
}

extern "C" void kernel_launch(void* const* d_in, const int* in_sizes, int n_in,
                              void* d_out, int out_size, void* d_ws, size_t ws_size,
                              hipStream_t stream) {
    const float* Cp  = (const float*)d_in[0];
    const float* Vp  = (const float*)d_in[1];
    const float* Wp  = (const float*)d_in[2];
    const float* TM  = (const float*)d_in[3];
    const float* Gam = (const float*)d_in[4];
    const float* Bet = (const float*)d_in[5];
    float* out = (float*)d_out;
    float* wsf = (float*)d_ws;

    // Workspace layout (floats): MQstep | Mc | Qc | POt | aIn | bInH  (~7.5 MB)
    const size_t f_mq   = (size_t)B * S * 2;        // 262144
    const size_t f_scG  = (size_t)B * NCG;          // 16384
    const size_t f_vecG = (size_t)B * NCG * D;      // 1048576
    const size_t f_po   = f_vecG;                   // 4B per chunk-d {P,O}
    const size_t f_binh = f_vecG / 2;               // fp16 carries
    const size_t needH  = (f_mq + 3 * f_scG + f_po + f_binh) * sizeof(float);

    if (ws_size >= needH) {
        float2* MQstep = (float2*)wsf;
        float*  Mc   = wsf + f_mq;
        float*  Qc   = Mc + f_scG;
        float*  POf  = Qc + f_scG;
        float*  aIn  = POf + f_po;
        float*  bInf = aIn + f_scG;
        H2x4*   POt  = (H2x4*)POf;
        H2x4*   bInH = (H2x4*)bInf;

        const dim3 blk(256);
        const dim3 grd(B * NCG / 16);           // 1024 blocks

        k1h<<<grd, blk, 0, stream>>>((const float4*)Cp, (const float4*)Vp,
                                     (const float4*)Wp, TM, MQstep, Mc, Qc, POt);
        k2<<<dim3(512 + 8), blk, 0, stream>>>(Mc, Qc, POt,
                                              (float4*)aIn, bInH);
        k3r<<<grd, blk, 0, stream>>>((const float4*)Cp, (const float4*)Vp,
                                     (const float4*)Wp, TM, Gam, Bet, MQstep,
                                     aIn, (const __half*)bInH, (float4*)out);
        return;
    }

    k_naive<<<dim3(B), dim3(64), 0, stream>>>(Cp, Vp, Wp, TM, Gam, Bet, out);
}

// Round 13
// 41.272 us; speedup vs baseline: 1.1924x; 1.1924x over previous
//
#include <hip/hip_runtime.h>
#include <hip/hip_fp16.h>

// Problem constants (match reference)
constexpr int B = 32, S = 4096, D = 64;
constexpr float EPS_DIV = 1e-8f;
constexpr float EPS_LN  = 1e-5f;

// Group-parallel decomposition: 16-lane groups, float4 channels (R8/R10 geometry)
constexpr int NCG = 512;         // sub-chunks per sequence
constexpr int LG  = S / NCG;     // 8 steps per sub-chunk
constexpr int CPL = NCG / 64;    // chunks per lane in phase-2 scans = 8
constexpr int BPB = NCG / 16;    // blocks per batch = 32

struct alignas(16) H2x4 { __half2 a, b, c, d; };   // 4x {hi,lo} half2

typedef float        f4v __attribute__((ext_vector_type(4)));
typedef unsigned int u2v __attribute__((ext_vector_type(2)));

__device__ __forceinline__ void nt_store_f4(float4 v, float4* p) {
    f4v t = {v.x, v.y, v.z, v.w};
    __builtin_nontemporal_store(t, (f4v*)p);
}

__device__ __forceinline__ float sigmoid_f(float x) {
    return __builtin_amdgcn_rcpf(1.f + __expf(-x));
}

// ---------------- Phase 1: summaries + fp16 {dg, ec*v} side-store ----------------
// Cross-lane reductions deferred out of the carried loop (R10 structure).
__global__ __launch_bounds__(256, 4) void k1h(
    const float4* __restrict__ C4, const float4* __restrict__ V4,
    const float4* __restrict__ W4, const float* __restrict__ TM,
    float2* __restrict__ MQstep,                        // [B*S]
    float*  __restrict__ Mc, float* __restrict__ Qc,    // [B*NCG]
    H2x4*   __restrict__ POt,                           // [B][D][NCG/4] fp16 {P,O}x4
    H2x4*   __restrict__ dgev)                          // [B*S*16] {dg,ev} quads
{
    __shared__ float sp[64][17];
    __shared__ float so[64][17];

    const int t = threadIdx.x;
    const int g = t >> 4;                  // group in block (= local c)
    const int r = t & 15;
    const int G = blockIdx.x * 16 + g;
    const int b = G >> 9;                  // / NCG
    const int c = G & (NCG - 1);
    const int c0 = (blockIdx.x & (BPB - 1)) * 16;
    const int s0 = c * LG;
    const size_t base = (size_t)(b * S + s0) * 16 + r;  // float4-quad index
    const float4 tm = reinterpret_cast<const float4*>(TM)[r];

    float psd[LG], pse[LG];                // per-lane partial sums (deferred)
    float4 P = {1.f, 1.f, 1.f, 1.f}, O = {0.f, 0.f, 0.f, 0.f};
#pragma unroll
    for (int i = 0; i < LG; ++i) {
        const size_t idx = base + (size_t)i * 16;
        const float4 w = W4[idx], cc = C4[idx], v = V4[idx];
        float4 dg, ec;
        dg.x = sigmoid_f(w.x * tm.x); dg.y = sigmoid_f(w.y * tm.y);
        dg.z = sigmoid_f(w.z * tm.z); dg.w = sigmoid_f(w.w * tm.w);
        ec.x = __expf(cc.x); ec.y = __expf(cc.y);
        ec.z = __expf(cc.z); ec.w = __expf(cc.w);
        psd[i] = (dg.x + dg.y) + (dg.z + dg.w);
        pse[i] = (ec.x + ec.y) + (ec.z + ec.w);
        // fp16-round {dg, ev}; ROUNDED values feed P/O so k2's carries
        // exactly match k3's replay inputs.
        H2x4 hq;
        hq.a = __floats2half2_rn(dg.x, ec.x * v.x);
        hq.b = __floats2half2_rn(dg.y, ec.y * v.y);
        hq.c = __floats2half2_rn(dg.z, ec.z * v.z);
        hq.d = __floats2half2_rn(dg.w, ec.w * v.w);
        dgev[idx] = hq;
        const float2 f0 = __half22float2(hq.a);
        const float2 f1 = __half22float2(hq.b);
        const float2 f2 = __half22float2(hq.c);
        const float2 f3 = __half22float2(hq.d);
        P.x *= f0.x; P.y *= f1.x; P.z *= f2.x; P.w *= f3.x;
        O.x = fmaf(f0.x, O.x, f0.y);
        O.y = fmaf(f1.x, O.y, f1.y);
        O.z = fmaf(f2.x, O.z, f2.y);
        O.w = fmaf(f3.x, O.w, f3.y);
    }

    // batched 16-lane butterflies (pipelined across LG chains)
#pragma unroll
    for (int m = 1; m < 16; m <<= 1) {
#pragma unroll
        for (int i = 0; i < LG; ++i) {
            psd[i] += __shfl_xor(psd[i], m, 64);
            pse[i] += __shfl_xor(pse[i], m, 64);
        }
    }
    float M = 1.f, Q = 0.f;
#pragma unroll
    for (int i = 0; i < LG; ++i) {
        const float mm = psd[i] * (1.f / 64.f);
        M *= mm;
        Q  = fmaf(mm, Q, pse[i]);
    }
    if (r == 0) {
#pragma unroll
        for (int i = 0; i < LG; ++i)
            MQstep[b * S + s0 + i] = make_float2(psd[i] * (1.f / 64.f), pse[i]);
        Mc[G] = M; Qc[G] = Q;
    }

    // transpose [16c x 64d] -> [64d x 16c] through LDS; pack fp16 {P,O}
    sp[4*r+0][g] = P.x; sp[4*r+1][g] = P.y; sp[4*r+2][g] = P.z; sp[4*r+3][g] = P.w;
    so[4*r+0][g] = O.x; so[4*r+1][g] = O.y; so[4*r+2][g] = O.z; so[4*r+3][g] = O.w;
    __syncthreads();
    const int d  = t >> 2;                 // 0..63
    const int cq = t & 3;                  // 0..3 (4 chunks each)
    H2x4 po;
    po.a = __floats2half2_rn(sp[d][cq*4+0], so[d][cq*4+0]);
    po.b = __floats2half2_rn(sp[d][cq*4+1], so[d][cq*4+1]);
    po.c = __floats2half2_rn(sp[d][cq*4+2], so[d][cq*4+2]);
    po.d = __floats2half2_rn(sp[d][cq*4+3], so[d][cq*4+3]);
    POt[(size_t)(b * D + d) * (NCG / 4) + (c0 >> 2) + cq] = po;
}

// ---------------- Phase 2: parallel affine scans (vector + scalar) ----------------
// Vector scan writes fp16 carries (regular cached loads/stores — no NT).
__global__ __launch_bounds__(256) void k2(
    const float*  __restrict__ Mc,  const float*  __restrict__ Qc,
    const H2x4*   __restrict__ POt,
    float4* __restrict__ aIn4,      // [B][NCG] fp32
    H2x4*   __restrict__ bInH)      // [B][D][NCG/8] fp16 carries
{
    const int wq   = threadIdx.x >> 6;
    const int lane = threadIdx.x & 63;

    if (blockIdx.x < 512) {
        const int W = blockIdx.x * 4 + wq;      // 0..2047
        const int b = W >> 6, d = W & 63;
        const size_t row4 = (size_t)(b * D + d) * (NCG / 4);
        const H2x4 A = POt[row4 + lane*2], Bq = POt[row4 + lane*2 + 1];
        float pj[CPL], oj[CPL];
        {
            float2 f;
            f = __half22float2(A.a);  pj[0] = f.x; oj[0] = f.y;
            f = __half22float2(A.b);  pj[1] = f.x; oj[1] = f.y;
            f = __half22float2(A.c);  pj[2] = f.x; oj[2] = f.y;
            f = __half22float2(A.d);  pj[3] = f.x; oj[3] = f.y;
            f = __half22float2(Bq.a); pj[4] = f.x; oj[4] = f.y;
            f = __half22float2(Bq.b); pj[5] = f.x; oj[5] = f.y;
            f = __half22float2(Bq.c); pj[6] = f.x; oj[6] = f.y;
            f = __half22float2(Bq.d); pj[7] = f.x; oj[7] = f.y;
        }
        float p = 1.f, o = 0.f;
#pragma unroll
        for (int j = 0; j < CPL; ++j) { o = fmaf(pj[j], o, oj[j]); p = pj[j] * p; }
#pragma unroll
        for (int s = 1; s < 64; s <<= 1) {
            const float pp = __shfl_up(p, s, 64);
            const float oo = __shfl_up(o, s, 64);
            if (lane >= s) { o = fmaf(p, oo, o); p = p * pp; }
        }
        float oe = __shfl_up(o, 1, 64);
        if (lane == 0) oe = 0.f;
        float bv = oe, ob[CPL];
#pragma unroll
        for (int j = 0; j < CPL; ++j) { ob[j] = bv; bv = fmaf(pj[j], bv, oj[j]); }
        H2x4 w;
        w.a = __floats2half2_rn(ob[0], ob[1]);
        w.b = __floats2half2_rn(ob[2], ob[3]);
        w.c = __floats2half2_rn(ob[4], ob[5]);
        w.d = __floats2half2_rn(ob[6], ob[7]);
        bInH[(size_t)(b * D + d) * (NCG / 8) + lane] = w;
    } else {
        const int v = (blockIdx.x - 512) * 4 + wq;
        if (v >= B) return;
        const float4* Mc4 = reinterpret_cast<const float4*>(Mc) + v * (NCG / 4);
        const float4* Qc4 = reinterpret_cast<const float4*>(Qc) + v * (NCG / 4);
        const float4 mA = Mc4[lane*2], mB = Mc4[lane*2 + 1];
        const float4 qA = Qc4[lane*2], qB = Qc4[lane*2 + 1];
        float mj[CPL] = {mA.x, mA.y, mA.z, mA.w, mB.x, mB.y, mB.z, mB.w};
        float qj[CPL] = {qA.x, qA.y, qA.z, qA.w, qB.x, qB.y, qB.z, qB.w};
        float m = 1.f, q = 0.f;
#pragma unroll
        for (int j = 0; j < CPL; ++j) { q = fmaf(mj[j], q, qj[j]); m = mj[j] * m; }
#pragma unroll
        for (int s = 1; s < 64; s <<= 1) {
            const float mm = __shfl_up(m, s, 64);
            const float qq = __shfl_up(q, s, 64);
            if (lane >= s) { q = fmaf(m, qq, q); m = m * mm; }
        }
        float qe = __shfl_up(q, 1, 64);
        if (lane == 0) qe = 0.f;
        float a = qe, ab[CPL];
#pragma unroll
        for (int j = 0; j < CPL; ++j) { ab[j] = a; a = fmaf(mj[j], a, qj[j]); }
        aIn4[v * (NCG / 4) + lane*2]     = make_float4(ab[0], ab[1], ab[2], ab[3]);
        aIn4[v * (NCG / 4) + lane*2 + 1] = make_float4(ab[4], ab[5], ab[6], ab[7]);
    }
}

// ---------------- Phase 3: replay from fp16 side-store + fused LayerNorm ----------------
// R10 deferred-LN structure; fp16 carry tile staged with regular loads.
__global__ __launch_bounds__(256, 4) void k3h(
    const H2x4* __restrict__ dgev,
    const float* __restrict__ Gam, const float* __restrict__ Bet,
    const float2* __restrict__ MQstep,
    const float* __restrict__ aIn, const __half* __restrict__ bInH,
    float4* __restrict__ out4)
{
    __shared__ float sb[64][17];   // [d][local c] carry tile (+1 pad)

    const int t = threadIdx.x;
    const int b  = blockIdx.x >> 5;            // BPB=32 blocks per batch
    const int c0 = (blockIdx.x & (BPB - 1)) * 16;
    {   // coalesced stage of this block's fp16 carry tile (8B per thread)
        const int d = t >> 2, cq = t & 3;
        const u2v raw = *reinterpret_cast<const u2v*>(
            bInH + (size_t)(b * D + d) * NCG + c0 + cq * 4);
        union { unsigned int u; __half2 h; } c0u, c1u;
        c0u.u = raw.x; c1u.u = raw.y;
        const float2 f0 = __half22float2(c0u.h);
        const float2 f1 = __half22float2(c1u.h);
        sb[d][cq*4+0] = f0.x; sb[d][cq*4+1] = f0.y;
        sb[d][cq*4+2] = f1.x; sb[d][cq*4+3] = f1.y;
    }
    __syncthreads();

    const int g = t >> 4;
    const int r = t & 15;
    const int c = c0 + g;
    const int s0 = c * LG;
    const size_t base = (size_t)(b * S + s0) * 16 + r;
    const float4 g4 = reinterpret_cast<const float4*>(Gam)[r];
    const float4 b4 = reinterpret_cast<const float4*>(Bet)[r];

    float a = aIn[b * NCG + c];                // broadcast within group
    float4 bv = make_float4(sb[4*r+0][g], sb[4*r+1][g],
                            sb[4*r+2][g], sb[4*r+3][g]);

    float4 yv[LG];
    float psy[LG], psq[LG];
#pragma unroll
    for (int i = 0; i < LG; ++i) {
        const size_t idx = base + (size_t)i * 16;
        const H2x4 hq = dgev[idx];
        const float2 f0 = __half22float2(hq.a);
        const float2 f1 = __half22float2(hq.b);
        const float2 f2 = __half22float2(hq.c);
        const float2 f3 = __half22float2(hq.d);
        const float2 mq = MQstep[b * S + s0 + i];   // uniform within group
        a = fmaf(mq.x, a, mq.y);
        bv.x = fmaf(f0.x, bv.x, f0.y);
        bv.y = fmaf(f1.x, bv.y, f1.y);
        bv.z = fmaf(f2.x, bv.z, f2.y);
        bv.w = fmaf(f3.x, bv.w, f3.y);
        const float inva = __builtin_amdgcn_rcpf(a + EPS_DIV);
        float4 y;
        y.x = bv.x * inva; y.y = bv.y * inva;
        y.z = bv.z * inva; y.w = bv.w * inva;
        yv[i] = y;
        psy[i] = (y.x + y.y) + (y.z + y.w);
        psq[i] = fmaf(y.x, y.x, y.y * y.y) + fmaf(y.z, y.z, y.w * y.w);
    }
#pragma unroll
    for (int m = 1; m < 16; m <<= 1) {
#pragma unroll
        for (int i = 0; i < LG; ++i) {
            psy[i] += __shfl_xor(psy[i], m, 64);
            psq[i] += __shfl_xor(psq[i], m, 64);
        }
    }
#pragma unroll
    for (int i = 0; i < LG; ++i) {
        const float4 y = yv[i];
        const float mu  = psy[i] * (1.f / 64.f);
        const float var = fmaf(-mu, mu, psq[i] * (1.f / 64.f));
        const float rs  = __builtin_amdgcn_rsqf(fmaxf(var, 0.f) + EPS_LN);
        float4 o;
        o.x = fmaf((y.x - mu) * rs, g4.x, b4.x);
        o.y = fmaf((y.y - mu) * rs, g4.y, b4.y);
        o.z = fmaf((y.z - mu) * rs, g4.z, b4.z);
        o.w = fmaf((y.w - mu) * rs, g4.w, b4.w);
        nt_store_f4(o, &out4[base + (size_t)i * 16]);
    }
}

// ---------------- Fallback (only if workspace unexpectedly small) ----------------
__global__ __launch_bounds__(64) void k_naive(
    const float* __restrict__ Cp, const float* __restrict__ Vp,
    const float* __restrict__ Wp, const float* __restrict__ TM,
    const float* __restrict__ Gam, const float* __restrict__ Bet,
    float* __restrict__ out)
{
    const int b = blockIdx.x;
    const int lane = threadIdx.x;
    const float tm = TM[lane], g = Gam[lane], bt = Bet[lane];
    float a = 0.f, bv = 0.f;
    for (int s = 0; s < S; ++s) {
        const size_t idx = ((size_t)b * S + s) * D + lane;
        const float wv = Wp[idx], cv = Cp[idx], vv = Vp[idx];
        const float dg = sigmoid_f(wv * tm);
        const float ec = __expf(cv);
        float sd = dg, se = ec;
#pragma unroll
        for (int m = 1; m < 64; m <<= 1) {
            sd += __shfl_xor(sd, m, 64);
            se += __shfl_xor(se, m, 64);
        }
        a  = fmaf(sd * (1.f / 64.f), a, se);
        bv = fmaf(dg, bv, ec * vv);
        const float y = bv * __builtin_amdgcn_rcpf(a + EPS_DIV);
        float sy = y, sq = y * y;
#pragma unroll
        for (int m = 1; m < 64; m <<= 1) {
            sy += __shfl_xor(sy, m, 64);
            sq += __shfl_xor(sq, m, 64);
        }
        const float mu  = sy * (1.f / 64.f);
        const float var = fmaf(-mu, mu, sq * (1.f / 64.f));
        const float rs  = __builtin_amdgcn_rsqf(fmaxf(var, 0.f) + EPS_LN);
        out[idx] = fmaf((y - mu) * rs, g, bt);
    }
}

extern "C" void kernel_launch(void* const* d_in, const int* in_sizes, int n_in,
                              void* d_out, int out_size, void* d_ws, size_t ws_size,
                              hipStream_t stream) {
    const float* Cp  = (const float*)d_in[0];
    const float* Vp  = (const float*)d_in[1];
    const float* Wp  = (const float*)d_in[2];
    const float* TM  = (const float*)d_in[3];
    const float* Gam = (const float*)d_in[4];
    const float* Bet = (const float*)d_in[5];
    float* out = (float*)d_out;
    float* wsf = (float*)d_ws;

    // Workspace layout (floats): MQstep | Mc | Qc | PO | aIn | bInH | dgev
    const size_t f_mq   = (size_t)B * S * 2;        // 262144
    const size_t f_scG  = (size_t)B * NCG;          // 16384
    const size_t f_vecG = (size_t)B * NCG * D;      // 1048576
    const size_t f_po   = f_vecG;                   // 4B per chunk {P,O}
    const size_t f_binh = f_vecG / 2;               // fp16 carries
    const size_t f_dgev = (size_t)B * S * D;        // 4B per elem {dg,ev}
    const size_t f_base = f_mq + 2 * f_scG + f_po + f_scG + f_binh;
    const size_t needH  = (f_base + f_dgev) * sizeof(float);   // ~39 MB

    if (ws_size >= needH) {
        float2* MQstep = (float2*)wsf;
        float*  Mc   = wsf + f_mq;
        float*  Qc   = Mc + f_scG;
        float*  POf  = Qc + f_scG;
        float*  aIn  = POf + f_po;
        float*  bInf = aIn + f_scG;
        H2x4*   dgev = (H2x4*)(wsf + f_base);
        H2x4*   POt  = (H2x4*)POf;
        H2x4*   bInH = (H2x4*)bInf;

        const dim3 blk(256);
        const dim3 grd(B * NCG / 16);           // 1024 blocks

        k1h<<<grd, blk, 0, stream>>>((const float4*)Cp, (const float4*)Vp,
                                     (const float4*)Wp, TM, MQstep, Mc, Qc,
                                     POt, dgev);
        k2<<<dim3(512 + 8), blk, 0, stream>>>(Mc, Qc, POt,
                                              (float4*)aIn, bInH);
        k3h<<<grd, blk, 0, stream>>>(dgev, Gam, Bet, MQstep,
                                     aIn, (const __half*)bInH, (float4*)out);
        return;
    }

    k_naive<<<dim3(B), dim3(64), 0, stream>>>(Cp, Vp, Wp, TM, Gam, Bet, out);
}